// Round 6
// baseline (61.855 us; speedup 1.0000x reference)
//
#include <hip/hip_runtime.h>
#include <hip/hip_bf16.h>

// GNNLayer: per-edge MLP score -> sampled segment-sum -> fc2 + BatchNorm.
// Algebra: sum(h@w2.T+b2, axis=1) == h . colsum(w2) + sum(b2); only the first
// min(64, group_len) edges per (sorted) head contribute.
// R4 lesson: cooperative grid.sync costs +27us under graph replay -> plain kernels.
// R5 lesson: monolithic edge kernel (5-barrier serial phase chain) stuck ~40us
// regardless of micro-opts -> split into score (MFMA) + gather (streaming).

#define D 128

typedef __attribute__((ext_vector_type(8))) short bf16x8;
typedef __attribute__((ext_vector_type(8))) unsigned short u16x8;
typedef __attribute__((ext_vector_type(4))) float f32x4;
typedef __attribute__((ext_vector_type(4))) unsigned short u16x4;

__device__ __forceinline__ unsigned short f2bf(float f) {
  union { float f; unsigned int u; } v; v.f = f;
  unsigned int r = v.u + 0x7FFFu + ((v.u >> 16) & 1u);
  return (unsigned short)(r >> 16);
}

// ---- prep: starts[] scatter, bf16 conversions, w2 colsum, b2 sum, x-copy ----
__global__ void prep_kernel(const float* __restrict__ w1,
                            const float* __restrict__ w2,
                            const float* __restrict__ b2,
                            const float* __restrict__ drug_emb,
                            const float* __restrict__ fc2_w,
                            const float* __restrict__ x,
                            const int* __restrict__ head,
                            unsigned short* __restrict__ w1b,
                            unsigned short* __restrict__ drugb,
                            unsigned short* __restrict__ fc2wb,
                            int* __restrict__ starts,
                            float* __restrict__ w2s,
                            float* __restrict__ b2sum,
                            float* __restrict__ out_hi,
                            int E_total, int n_drug, int total) {
  int g = blockIdx.x * 256 + threadIdx.x;
  if (g < E_total) {
    int h1 = head[g];
    int h0 = (g == 0) ? -1 : head[g - 1];
    for (int d = h0 + 1; d <= h1; ++d) starts[d] = g;   // usually 0 iters
    if (g == E_total - 1) {
      for (int d = h1 + 1; d <= n_drug; ++d) starts[d] = E_total;
    }
  }
  if (g < D * D) w1b[g] = f2bf(w1[g]);
  if (g < 2 * D * D) fc2wb[g] = f2bf(fc2_w[g]);
  if (g < n_drug * D) drugb[g] = f2bf(drug_emb[g]);
  if (g < total) out_hi[g] = x[g];
  if (g < D) {
    float s = 0.f;
    for (int j = 0; j < D; ++j) s += w2[j * D + g];
    w2s[g] = s;
  }
  if (g == 0) {
    float s = 0.f;
    for (int j = 0; j < D; ++j) s += b2[j];
    b2sum[0] = s;
  }
}

// ---- score: had = drug*rel -> z = had@w1^T + b1 (bf16 MFMA) -> sigmoid
// ---- -> scores[n*64+e] = h.w2s + b2sum. 512 threads: wave w owns j-tile w. ----
__global__ __launch_bounds__(512, 2) void score_kernel(
    const float* __restrict__ drug_emb, const float* __restrict__ rel_emb,
    const float* __restrict__ b1, const int* __restrict__ dkg_rel,
    const int* __restrict__ starts, const unsigned short* __restrict__ w1b,
    const float* __restrict__ w2s, const float* __restrict__ b2sum,
    const int* __restrict__ samp, float* __restrict__ scores) {
  const int n = blockIdx.x;
  const int tid = threadIdx.x;
  const int w = tid >> 6, lane = tid & 63;
  const int fl = lane & 15, kh = lane >> 4;
  const int g = tid >> 5, l5 = tid & 31;   // 16 groups x 32 lanes

  __shared__ __align__(16) unsigned short hadb[64][136];  // 272B row: 2-way alias only
  __shared__ float scorePart[8][64];
  __shared__ int relIdx[64];

  const int base = starts[n];
  const int end  = starts[n + 1];
  int ss = samp[0]; if (ss > 64) ss = 64;
  int cnt = end - base; if (cnt > ss) cnt = ss; if (cnt < 0) cnt = 0;

  if (tid < 64) relIdx[tid] = (tid < cnt) ? dkg_rel[base + tid] : 0;

  const f32x4 dr = *(const f32x4*)(drug_emb + (long)n * D + l5 * 4);

  // B fragments: wave w owns feature tile w (16 features)
  bf16x8 bfr[4];
  const int f = w * 16 + fl;
  const float w2sr = w2s[f];
  const float b1r  = b1[f];
  #pragma unroll
  for (int kt = 0; kt < 4; ++kt)
    bfr[kt] = *(const bf16x8*)(w1b + f * D + kt * 32 + kh * 8);
  const float b2s = b2sum[0];

  __syncthreads();  // relIdx ready

  // stage had (bf16): group g handles edges it*16+g
  #pragma unroll
  for (int it = 0; it < 4; ++it) {
    int e = it * 16 + g;
    int r = relIdx[e];
    f32x4 rl = *(const f32x4*)(rel_emb + (long)r * D + l5 * 4);
    f32x4 v = dr * rl;
    u16x4 pk = { f2bf(v.x), f2bf(v.y), f2bf(v.z), f2bf(v.w) };
    *(u16x4*)&hadb[e][l5 * 4] = pk;
  }
  __syncthreads();  // hadb ready

  f32x4 acc[4];
  #pragma unroll
  for (int mt = 0; mt < 4; ++mt)
    acc[mt] = (f32x4){b1r, b1r, b1r, b1r};

  #pragma unroll
  for (int kt = 0; kt < 4; ++kt) {
    bf16x8 af[4];
    #pragma unroll
    for (int mt = 0; mt < 4; ++mt)
      af[mt] = *(const bf16x8*)&hadb[mt * 16 + fl][kt * 32 + kh * 8];
    #pragma unroll
    for (int mt = 0; mt < 4; ++mt)
      acc[mt] = __builtin_amdgcn_mfma_f32_16x16x32_bf16(af[mt], bfr[kt], acc[mt], 0, 0, 0);
  }

  // epilogue: sigmoid, weight by w2s, reduce across this j-tile's 16 features
  #pragma unroll
  for (int mt = 0; mt < 4; ++mt) {
    #pragma unroll
    for (int r = 0; r < 4; ++r) {
      float hh = 1.f / (1.f + __expf(-acc[mt][r]));
      float p = hh * w2sr;
      p += __shfl_xor(p, 1);
      p += __shfl_xor(p, 2);
      p += __shfl_xor(p, 4);
      p += __shfl_xor(p, 8);
      if (fl == 0) scorePart[w][mt * 16 + kh * 4 + r] = p;
    }
  }
  __syncthreads();

  if (tid < 64) {
    float sc = b2s;
    #pragma unroll
    for (int q = 0; q < 8; ++q) sc += scorePart[q][tid];
    scores[(long)n * 64 + tid] = sc;   // garbage for tid>=cnt, masked downstream
  }
}

// ---- gather: neigh[n] = sum_e score[e] * tail_emb[tails[e]] (bf16 out) ----
// Two dependent memory stages; 8 groups x 8 unconditional float4 gathers.
__global__ __launch_bounds__(256, 4) void gather_kernel(
    const float* __restrict__ tail_emb, const int* __restrict__ dkg_tail,
    const int* __restrict__ starts, const float* __restrict__ scores,
    const int* __restrict__ samp, unsigned short* __restrict__ neighb) {
  const int n = blockIdx.x;
  const int tid = threadIdx.x;
  const int g = tid >> 5, l5 = tid & 31;   // 8 groups x 32 lanes

  __shared__ float scoreL[64];
  __shared__ int   tails[64];
  __shared__ __align__(16) float gpart[8 * 128];

  const int base = starts[n];
  const int end  = starts[n + 1];
  int ss = samp[0]; if (ss > 64) ss = 64;
  int cnt = end - base; if (cnt > ss) cnt = ss; if (cnt < 0) cnt = 0;

  if (tid < 64) {
    tails[tid]  = (tid < cnt) ? dkg_tail[base + tid] : 0;
    scoreL[tid] = (tid < cnt) ? scores[(long)n * 64 + tid] : 0.f;
  }
  __syncthreads();

  f32x4 a = (f32x4){0.f, 0.f, 0.f, 0.f};
  #pragma unroll
  for (int it = 0; it < 8; ++it) {
    int e = it * 8 + g;
    f32x4 row = *(const f32x4*)(tail_emb + (long)tails[e] * D + l5 * 4);
    a += row * scoreL[e];              // scoreL=0 masks e>=cnt
  }
  ((f32x4*)gpart)[g * 32 + l5] = a;
  __syncthreads();

  if (tid < D) {
    float s = 0.f;
    #pragma unroll
    for (int q = 0; q < 8; ++q) s += gpart[q * 128 + tid];
    neighb[(long)n * D + tid] = f2bf(s);
  }
}

// ---- fc2 via bf16 MFMA + fused BN partial stats: 64 rows/block ----
__global__ __launch_bounds__(256, 1) void fc2s_kernel(
    const unsigned short* __restrict__ drugb, const unsigned short* __restrict__ neighb,
    const unsigned short* __restrict__ fc2wb, const float* __restrict__ fc2_b,
    float* __restrict__ out_pre, float* __restrict__ partial, int n_drug) {
  const int tid = threadIdx.x;
  const int w = tid >> 6, lane = tid & 63;
  const int fl = lane & 15, kh = lane >> 4;
  const int n0 = blockIdx.x * 64;

  __shared__ __align__(16) unsigned short asmem[64][264];  // 528B row stride: 2-way alias only

  #pragma unroll
  for (int it = 0; it < 8; ++it) {
    int c = it * 256 + tid;
    int row = c >> 5;
    int off = (c & 31) * 16;
    int gr = n0 + row;
    u16x8 v = (u16x8){0,0,0,0,0,0,0,0};
    if (gr < n_drug) {
      const unsigned short* src = (off < 256) ? (drugb + (long)gr * D + (off >> 1))
                                              : (neighb + (long)gr * D + ((off - 256) >> 1));
      v = *(const u16x8*)src;
    }
    *(u16x8*)((char*)&asmem[0][0] + row * 528 + off) = v;
  }

  bf16x8 bfr[2][8];
  float bjr[2];
  #pragma unroll
  for (int jq = 0; jq < 2; ++jq) {
    int f = (w * 2 + jq) * 16 + fl;
    bjr[jq] = fc2_b[f];
    #pragma unroll
    for (int kt = 0; kt < 8; ++kt)
      bfr[jq][kt] = *(const bf16x8*)(fc2wb + (long)f * 256 + kt * 32 + kh * 8);
  }
  __syncthreads();

  f32x4 acc[4][2];
  #pragma unroll
  for (int mt = 0; mt < 4; ++mt)
    #pragma unroll
    for (int jq = 0; jq < 2; ++jq)
      acc[mt][jq] = (f32x4){bjr[jq], bjr[jq], bjr[jq], bjr[jq]};

  #pragma unroll
  for (int kt = 0; kt < 8; ++kt) {
    bf16x8 af[4];
    #pragma unroll
    for (int mt = 0; mt < 4; ++mt)
      af[mt] = *(const bf16x8*)((char*)&asmem[0][0] + (mt * 16 + fl) * 528 + kt * 64 + kh * 16);
    #pragma unroll
    for (int mt = 0; mt < 4; ++mt)
      #pragma unroll
      for (int jq = 0; jq < 2; ++jq)
        acc[mt][jq] = __builtin_amdgcn_mfma_f32_16x16x32_bf16(af[mt], bfr[jq][kt], acc[mt][jq], 0, 0, 0);
  }

  #pragma unroll
  for (int jq = 0; jq < 2; ++jq) {
    int j = (w * 2 + jq) * 16 + fl;
    float s = 0.f, s2 = 0.f;
    #pragma unroll
    for (int mt = 0; mt < 4; ++mt) {
      #pragma unroll
      for (int r = 0; r < 4; ++r) {
        int grow = n0 + mt * 16 + kh * 4 + r;
        float v = acc[mt][jq][r];
        if (grow < n_drug) {
          out_pre[(long)grow * D + j] = v;
          s += v; s2 += v * v;
        }
      }
    }
    s  += __shfl_xor(s, 16);  s  += __shfl_xor(s, 32);
    s2 += __shfl_xor(s2, 16); s2 += __shfl_xor(s2, 32);
    if (kh == 0)
      ((float2*)partial)[(long)blockIdx.x * D + j] = make_float2(s, s2);
  }
}

// ---- fused BN final reduce + normalize: 8 rows/block ----
__global__ void bnfin_kernel(const float* __restrict__ out_pre,
                             const float* __restrict__ partial,
                             const float* __restrict__ gamma,
                             const float* __restrict__ beta,
                             float* __restrict__ out,
                             int n_drug, int nblocks) {
  const int tid = threadIdx.x;
  const int j = tid & 127, h = tid >> 7;
  const int n0 = blockIdx.x * 8 + h * 4;

  float v[4];
  #pragma unroll
  for (int r = 0; r < 4; ++r)
    v[r] = out_pre[(long)(n0 + r) * D + j];

  float s = 0.f, s2 = 0.f;
  for (int b = 0; b < nblocks; ++b) {
    float2 p = ((const float2*)partial)[(long)b * D + j];
    s += p.x; s2 += p.y;
  }
  float mean = s / (float)n_drug;
  float var  = s2 / (float)n_drug - mean * mean;
  float inv  = rsqrtf(var + 1e-5f);
  float sc   = inv * gamma[j];
  float sh   = beta[j] - mean * sc;

  #pragma unroll
  for (int r = 0; r < 4; ++r)
    out[(long)(n0 + r) * D + j] = v[r] * sc + sh;
}

extern "C" void kernel_launch(void* const* d_in, const int* in_sizes, int n_in,
                              void* d_out, int out_size, void* d_ws, size_t ws_size,
                              hipStream_t stream) {
  const float* drug_emb = (const float*)d_in[0];
  const float* rel_emb  = (const float*)d_in[1];
  const float* tail_emb = (const float*)d_in[2];
  const float* w1       = (const float*)d_in[3];
  const float* b1       = (const float*)d_in[4];
  const float* w2       = (const float*)d_in[5];
  const float* b2       = (const float*)d_in[6];
  const float* fc2_w    = (const float*)d_in[7];
  const float* fc2_b    = (const float*)d_in[8];
  const float* gamma    = (const float*)d_in[9];
  const float* beta     = (const float*)d_in[10];
  const float* x        = (const float*)d_in[11];
  const int*   dkg_head = (const int*)d_in[12];
  const int*   dkg_rel  = (const int*)d_in[13];
  const int*   dkg_tail = (const int*)d_in[14];
  const int*   samp     = (const int*)d_in[15];

  const int n_drug = in_sizes[0] / D;   // 2000
  const int E      = in_sizes[12];      // 500000
  float* out = (float*)d_out;
  const int total = out_size / 2;       // 256000

  // workspace layout
  char* ws = (char*)d_ws;
  int*            starts  = (int*)(ws + 0);                     // 8004 B
  unsigned short* w1b     = (unsigned short*)(ws + 8192);       // 32768 B
  float*          w2s     = (float*)(ws + 40960);               // 512 B
  float*          b2sum   = (float*)(ws + 41472);               // 4 B
  unsigned short* fc2wb   = (unsigned short*)(ws + 49152);      // 65536 B
  unsigned short* drugb   = (unsigned short*)(ws + 131072);     // 512000 B
  unsigned short* neighb  = (unsigned short*)(ws + 655360);     // 512000 B
  float*          out_pre = (float*)(ws + 1179648);             // 1024000 B
  float*          partial = (float*)(ws + 2228224);             // 32768 B
  float*          scores  = (float*)(ws + 2260992);             // 512000 B

  const int nbf = (n_drug + 63) / 64;   // 32 fc2s blocks

  hipLaunchKernelGGL(prep_kernel, dim3((E + 256) / 256), dim3(256), 0, stream,
                     w1, w2, b2, drug_emb, fc2_w, x, dkg_head,
                     w1b, drugb, fc2wb, starts, w2s, b2sum, out + total,
                     E, n_drug, total);
  hipLaunchKernelGGL(score_kernel, dim3(n_drug), dim3(512), 0, stream,
                     drug_emb, rel_emb, b1, dkg_rel, starts, w1b, w2s, b2sum,
                     samp, scores);
  hipLaunchKernelGGL(gather_kernel, dim3(n_drug), dim3(256), 0, stream,
                     tail_emb, dkg_tail, starts, scores, samp, neighb);
  hipLaunchKernelGGL(fc2s_kernel, dim3(nbf), dim3(256), 0, stream,
                     drugb, neighb, fc2wb, fc2_b, out_pre, partial, n_drug);
  hipLaunchKernelGGL(bnfin_kernel, dim3(n_drug / 8), dim3(256), 0, stream,
                     out_pre, partial, gamma, beta, out, n_drug, nbf);
}

// Round 7
// 49.357 us; speedup vs baseline: 1.2532x; 1.2532x over previous
//
#include <hip/hip_runtime.h>
#include <hip/hip_bf16.h>

// GNNLayer: per-edge MLP score -> sampled segment-sum -> fc2 + BatchNorm.
// Algebra: sum(h@w2.T+b2, axis=1) == h . colsum(w2) + sum(b2); only the first
// min(64, group_len) edges per (sorted) head contribute.
// R4 lesson: cooperative grid.sync costs +27us under graph replay -> plain kernels.
// R6 lesson: splitting edge into score+gather cost +9.4us (kernel boundary kills
// block-level phase pipelining) -> monolithic edge kept.
// R7: parallelize prep's serial reduction loops (w2 colsum had a serial
// accumulator chain; b2sum was 128 dependent loads on ONE thread).

#define D 128

typedef __attribute__((ext_vector_type(8))) short bf16x8;
typedef __attribute__((ext_vector_type(8))) unsigned short u16x8;
typedef __attribute__((ext_vector_type(4))) float f32x4;
typedef __attribute__((ext_vector_type(4))) unsigned short u16x4;

__device__ __forceinline__ unsigned short f2bf(float f) {
  union { float f; unsigned int u; } v; v.f = f;
  unsigned int r = v.u + 0x7FFFu + ((v.u >> 16) & 1u);
  return (unsigned short)(r >> 16);
}

// ---- prep: starts[] scatter, bf16 conversions, w2 colsum, b2 sum, x-copy ----
__global__ void prep_kernel(const float* __restrict__ w1,
                            const float* __restrict__ w2,
                            const float* __restrict__ b2,
                            const float* __restrict__ drug_emb,
                            const float* __restrict__ fc2_w,
                            const float* __restrict__ x,
                            const int* __restrict__ head,
                            unsigned short* __restrict__ w1b,
                            unsigned short* __restrict__ drugb,
                            unsigned short* __restrict__ fc2wb,
                            int* __restrict__ starts,
                            float* __restrict__ w2s,
                            float* __restrict__ b2sum,
                            float* __restrict__ out_hi,
                            int E_total, int n_drug, int total) {
  int g = blockIdx.x * 256 + threadIdx.x;
  if (g < E_total) {
    int h1 = head[g];
    int h0 = (g == 0) ? -1 : head[g - 1];
    for (int d = h0 + 1; d <= h1; ++d) starts[d] = g;   // usually 0 iters
    if (g == E_total - 1) {
      for (int d = h1 + 1; d <= n_drug; ++d) starts[d] = E_total;
    }
  }
  if (g < D * D) w1b[g] = f2bf(w1[g]);
  if (g < 2 * D * D) fc2wb[g] = f2bf(fc2_w[g]);
  if (g < n_drug * D) drugb[g] = f2bf(drug_emb[g]);
  if (g < total) out_hi[g] = x[g];
  // w2 colsum: 8 independent partial accumulators -> loads fully pipelined
  if (g < D) {
    float s0=0.f,s1=0.f,s2=0.f,s3=0.f,s4=0.f,s5=0.f,s6=0.f,s7=0.f;
    #pragma unroll
    for (int j = 0; j < D; j += 8) {
      s0 += w2[(j+0)*D+g]; s1 += w2[(j+1)*D+g];
      s2 += w2[(j+2)*D+g]; s3 += w2[(j+3)*D+g];
      s4 += w2[(j+4)*D+g]; s5 += w2[(j+5)*D+g];
      s6 += w2[(j+6)*D+g]; s7 += w2[(j+7)*D+g];
    }
    w2s[g] = ((s0+s1)+(s2+s3))+((s4+s5)+(s6+s7));
  }
  // b2 sum: wave 0 of block 0, parallel shuffle reduce (was 1 thread x 128 loads)
  if (g < 64) {
    float v = b2[g] + b2[g + 64];
    v += __shfl_xor(v, 1);  v += __shfl_xor(v, 2);  v += __shfl_xor(v, 4);
    v += __shfl_xor(v, 8);  v += __shfl_xor(v, 16); v += __shfl_xor(v, 32);
    if (g == 0) b2sum[0] = v;
  }
}

// ---- per-drug: had = drug*rel -> z = had@w1^T + b1 (bf16 MFMA) -> sigmoid
// ---- -> score = h.w2s + b2sum -> neigh = sum score*tail (bf16 out) ----
// T14: tail rows prefetched into registers before the MFMA phase.
__global__ __launch_bounds__(256, 2) void edge_kernel(
    const float* __restrict__ drug_emb, const float* __restrict__ rel_emb,
    const float* __restrict__ tail_emb, const float* __restrict__ b1,
    const int* __restrict__ dkg_rel, const int* __restrict__ dkg_tail,
    const int* __restrict__ starts, const unsigned short* __restrict__ w1b,
    const float* __restrict__ w2s, const float* __restrict__ b2sum,
    const int* __restrict__ samp, unsigned short* __restrict__ neighb) {
  const int n = blockIdx.x;
  const int tid = threadIdx.x;
  const int w = tid >> 6, lane = tid & 63;
  const int fl = lane & 15, kh = lane >> 4;
  const int g = tid >> 5, l5 = tid & 31;   // 8 groups x 32 lanes

  __shared__ __align__(16) unsigned short hadb[64][136];  // 272B row: 2-way alias only
  __shared__ float scorePart[4][64];
  __shared__ float scoreL[64];
  __shared__ int   tails[64];
  __shared__ int   relIdx[64];
  float* gpart = (float*)&hadb[0][0];  // alias: gather partials (4KB), reused after MFMA phase

  const int base = starts[n];
  const int end  = starts[n + 1];
  int ss = samp[0]; if (ss > 64) ss = 64;
  int cnt = end - base; if (cnt > ss) cnt = ss; if (cnt < 0) cnt = 0;

  if (tid < 64) {
    tails[tid]  = (tid < cnt) ? dkg_tail[base + tid] : 0;
    relIdx[tid] = (tid < cnt) ? dkg_rel[base + tid] : 0;
  }

  const f32x4 dr = *(const f32x4*)(drug_emb + (long)n * D + l5 * 4);

  // B fragments: wave w covers feature tiles {2w, 2w+1}
  bf16x8 bfr[2][4];
  float w2sr[2], b1r[2];
  #pragma unroll
  for (int jq = 0; jq < 2; ++jq) {
    int f = (w * 2 + jq) * 16 + fl;
    w2sr[jq] = w2s[f];
    b1r[jq]  = b1[f];
    #pragma unroll
    for (int kt = 0; kt < 4; ++kt)
      bfr[jq][kt] = *(const bf16x8*)(w1b + f * D + kt * 32 + kh * 8);
  }
  const float b2s = b2sum[0];

  __syncthreads();  // relIdx/tails ready

  // stage had (bf16): group g handles edges it*8+g; 32 lanes cover 128 feats
  #pragma unroll
  for (int it = 0; it < 8; ++it) {
    int e = it * 8 + g;
    int r = relIdx[e];
    f32x4 rl = *(const f32x4*)(rel_emb + (long)r * D + l5 * 4);
    f32x4 v = dr * rl;
    u16x4 pk = { f2bf(v.x), f2bf(v.y), f2bf(v.z), f2bf(v.w) };
    *(u16x4*)&hadb[e][l5 * 4] = pk;
  }

  // T14: issue tail-row loads now; consumed after the score barrier.
  f32x4 trow[8];
  #pragma unroll
  for (int it = 0; it < 8; ++it) {
    int e = it * 8 + g;
    trow[it] = *(const f32x4*)(tail_emb + (long)tails[e] * D + l5 * 4);
  }

  __syncthreads();  // hadb ready

  f32x4 acc[4][2];
  #pragma unroll
  for (int mt = 0; mt < 4; ++mt)
    #pragma unroll
    for (int jq = 0; jq < 2; ++jq)
      acc[mt][jq] = (f32x4){b1r[jq], b1r[jq], b1r[jq], b1r[jq]};

  #pragma unroll
  for (int kt = 0; kt < 4; ++kt) {
    bf16x8 af[4];
    #pragma unroll
    for (int mt = 0; mt < 4; ++mt)
      af[mt] = *(const bf16x8*)&hadb[mt * 16 + fl][kt * 32 + kh * 8];
    #pragma unroll
    for (int mt = 0; mt < 4; ++mt)
      #pragma unroll
      for (int jq = 0; jq < 2; ++jq)
        acc[mt][jq] = __builtin_amdgcn_mfma_f32_16x16x32_bf16(af[mt], bfr[jq][kt], acc[mt][jq], 0, 0, 0);
  }

  // epilogue: sigmoid, partial score over this wave's 32 features, 16-lane reduce
  #pragma unroll
  for (int mt = 0; mt < 4; ++mt) {
    #pragma unroll
    for (int r = 0; r < 4; ++r) {
      float p = 0.f;
      #pragma unroll
      for (int jq = 0; jq < 2; ++jq) {
        float hh = 1.f / (1.f + __expf(-acc[mt][jq][r]));
        p += hh * w2sr[jq];
      }
      p += __shfl_xor(p, 1);
      p += __shfl_xor(p, 2);
      p += __shfl_xor(p, 4);
      p += __shfl_xor(p, 8);
      if (fl == 0) scorePart[w][mt * 16 + kh * 4 + r] = p;
    }
  }
  __syncthreads();

  if (tid < 64) {
    float sc = scorePart[0][tid] + scorePart[1][tid] + scorePart[2][tid] + scorePart[3][tid] + b2s;
    scoreL[tid] = (tid < cnt) ? sc : 0.f;
  }
  __syncthreads();

  // weighted accumulate of prefetched tail rows
  f32x4 a = (f32x4){0.f, 0.f, 0.f, 0.f};
  #pragma unroll
  for (int it = 0; it < 8; ++it) {
    int e = it * 8 + g;
    float s = scoreL[e];            // 0 for e >= cnt
    a += trow[it] * s;
  }
  ((f32x4*)gpart)[g * 32 + l5] = a;
  __syncthreads();

  if (tid < D) {
    float s = 0.f;
    #pragma unroll
    for (int q = 0; q < 8; ++q) s += gpart[q * 128 + tid];
    neighb[(long)n * D + tid] = f2bf(s);
  }
}

// ---- fc2 via bf16 MFMA + fused BN partial stats: 64 rows/block ----
__global__ __launch_bounds__(256, 1) void fc2s_kernel(
    const unsigned short* __restrict__ drugb, const unsigned short* __restrict__ neighb,
    const unsigned short* __restrict__ fc2wb, const float* __restrict__ fc2_b,
    float* __restrict__ out_pre, float* __restrict__ partial, int n_drug) {
  const int tid = threadIdx.x;
  const int w = tid >> 6, lane = tid & 63;
  const int fl = lane & 15, kh = lane >> 4;
  const int n0 = blockIdx.x * 64;

  __shared__ __align__(16) unsigned short asmem[64][264];  // 528B row stride: 2-way alias only

  #pragma unroll
  for (int it = 0; it < 8; ++it) {
    int c = it * 256 + tid;
    int row = c >> 5;
    int off = (c & 31) * 16;
    int gr = n0 + row;
    u16x8 v = (u16x8){0,0,0,0,0,0,0,0};
    if (gr < n_drug) {
      const unsigned short* src = (off < 256) ? (drugb + (long)gr * D + (off >> 1))
                                              : (neighb + (long)gr * D + ((off - 256) >> 1));
      v = *(const u16x8*)src;
    }
    *(u16x8*)((char*)&asmem[0][0] + row * 528 + off) = v;
  }

  bf16x8 bfr[2][8];
  float bjr[2];
  #pragma unroll
  for (int jq = 0; jq < 2; ++jq) {
    int f = (w * 2 + jq) * 16 + fl;
    bjr[jq] = fc2_b[f];
    #pragma unroll
    for (int kt = 0; kt < 8; ++kt)
      bfr[jq][kt] = *(const bf16x8*)(fc2wb + (long)f * 256 + kt * 32 + kh * 8);
  }
  __syncthreads();

  f32x4 acc[4][2];
  #pragma unroll
  for (int mt = 0; mt < 4; ++mt)
    #pragma unroll
    for (int jq = 0; jq < 2; ++jq)
      acc[mt][jq] = (f32x4){bjr[jq], bjr[jq], bjr[jq], bjr[jq]};

  #pragma unroll
  for (int kt = 0; kt < 8; ++kt) {
    bf16x8 af[4];
    #pragma unroll
    for (int mt = 0; mt < 4; ++mt)
      af[mt] = *(const bf16x8*)((char*)&asmem[0][0] + (mt * 16 + fl) * 528 + kt * 64 + kh * 16);
    #pragma unroll
    for (int mt = 0; mt < 4; ++mt)
      #pragma unroll
      for (int jq = 0; jq < 2; ++jq)
        acc[mt][jq] = __builtin_amdgcn_mfma_f32_16x16x32_bf16(af[mt], bfr[jq][kt], acc[mt][jq], 0, 0, 0);
  }

  #pragma unroll
  for (int jq = 0; jq < 2; ++jq) {
    int j = (w * 2 + jq) * 16 + fl;
    float s = 0.f, s2 = 0.f;
    #pragma unroll
    for (int mt = 0; mt < 4; ++mt) {
      #pragma unroll
      for (int r = 0; r < 4; ++r) {
        int grow = n0 + mt * 16 + kh * 4 + r;
        float v = acc[mt][jq][r];
        if (grow < n_drug) {
          out_pre[(long)grow * D + j] = v;
          s += v; s2 += v * v;
        }
      }
    }
    s  += __shfl_xor(s, 16);  s  += __shfl_xor(s, 32);
    s2 += __shfl_xor(s2, 16); s2 += __shfl_xor(s2, 32);
    if (kh == 0)
      ((float2*)partial)[(long)blockIdx.x * D + j] = make_float2(s, s2);
  }
}

// ---- fused BN final reduce + normalize: 8 rows/block ----
__global__ void bnfin_kernel(const float* __restrict__ out_pre,
                             const float* __restrict__ partial,
                             const float* __restrict__ gamma,
                             const float* __restrict__ beta,
                             float* __restrict__ out,
                             int n_drug, int nblocks) {
  const int tid = threadIdx.x;
  const int j = tid & 127, h = tid >> 7;
  const int n0 = blockIdx.x * 8 + h * 4;

  float v[4];
  #pragma unroll
  for (int r = 0; r < 4; ++r)
    v[r] = out_pre[(long)(n0 + r) * D + j];

  float s = 0.f, s2 = 0.f;
  for (int b = 0; b < nblocks; ++b) {
    float2 p = ((const float2*)partial)[(long)b * D + j];
    s += p.x; s2 += p.y;
  }
  float mean = s / (float)n_drug;
  float var  = s2 / (float)n_drug - mean * mean;
  float inv  = rsqrtf(var + 1e-5f);
  float sc   = inv * gamma[j];
  float sh   = beta[j] - mean * sc;

  #pragma unroll
  for (int r = 0; r < 4; ++r)
    out[(long)(n0 + r) * D + j] = v[r] * sc + sh;
}

extern "C" void kernel_launch(void* const* d_in, const int* in_sizes, int n_in,
                              void* d_out, int out_size, void* d_ws, size_t ws_size,
                              hipStream_t stream) {
  const float* drug_emb = (const float*)d_in[0];
  const float* rel_emb  = (const float*)d_in[1];
  const float* tail_emb = (const float*)d_in[2];
  const float* w1       = (const float*)d_in[3];
  const float* b1       = (const float*)d_in[4];
  const float* w2       = (const float*)d_in[5];
  const float* b2       = (const float*)d_in[6];
  const float* fc2_w    = (const float*)d_in[7];
  const float* fc2_b    = (const float*)d_in[8];
  const float* gamma    = (const float*)d_in[9];
  const float* beta     = (const float*)d_in[10];
  const float* x        = (const float*)d_in[11];
  const int*   dkg_head = (const int*)d_in[12];
  const int*   dkg_rel  = (const int*)d_in[13];
  const int*   dkg_tail = (const int*)d_in[14];
  const int*   samp     = (const int*)d_in[15];

  const int n_drug = in_sizes[0] / D;   // 2000
  const int E      = in_sizes[12];      // 500000
  float* out = (float*)d_out;
  const int total = out_size / 2;       // 256000

  // workspace layout
  char* ws = (char*)d_ws;
  int*            starts  = (int*)(ws + 0);                     // 8004 B
  unsigned short* w1b     = (unsigned short*)(ws + 8192);       // 32768 B
  float*          w2s     = (float*)(ws + 40960);               // 512 B
  float*          b2sum   = (float*)(ws + 41472);               // 4 B
  unsigned short* fc2wb   = (unsigned short*)(ws + 49152);      // 65536 B
  unsigned short* drugb   = (unsigned short*)(ws + 131072);     // 512000 B
  unsigned short* neighb  = (unsigned short*)(ws + 655360);     // 512000 B
  float*          out_pre = (float*)(ws + 1179648);             // 1024000 B
  float*          partial = (float*)(ws + 2228224);             // 32768 B

  const int nbf = (n_drug + 63) / 64;   // 32 fc2s blocks

  hipLaunchKernelGGL(prep_kernel, dim3((E + 256) / 256), dim3(256), 0, stream,
                     w1, w2, b2, drug_emb, fc2_w, x, dkg_head,
                     w1b, drugb, fc2wb, starts, w2s, b2sum, out + total,
                     E, n_drug, total);
  hipLaunchKernelGGL(edge_kernel, dim3(n_drug), dim3(256), 0, stream,
                     drug_emb, rel_emb, tail_emb, b1, dkg_rel, dkg_tail,
                     starts, w1b, w2s, b2sum, samp, neighb);
  hipLaunchKernelGGL(fc2s_kernel, dim3(nbf), dim3(256), 0, stream,
                     drugb, neighb, fc2wb, fc2_b, out_pre, partial, n_drug);
  hipLaunchKernelGGL(bnfin_kernel, dim3(n_drug / 8), dim3(256), 0, stream,
                     out_pre, partial, gamma, beta, out, n_drug, nbf);
}